// Round 1
// baseline (453.041 us; speedup 1.0000x reference)
//
#include <hip/hip_runtime.h>
#include <math.h>

#define N_NODES   50000
#define N_EDGES   400000
#define NCH       16
#define CAP       48          // per-node edge capacity; P(deg>48 | lambda=8) ~ 1e-17
#define NSTRIPE   8
#define TPB       256
#define NBN       ((N_NODES + TPB - 1) / TPB)   // 196
#define NB_EDGES  ((N_EDGES + TPB - 1) / TPB)   // 1563
#define NBLK_MAIN 4096        // persistent grid for node_wave_fast (16384 waves)

// ======================= FAST PATH (bucketed, 3 dispatches) =======================

// K1: per-edge geometry + direct bucket write (no scan/fill phases)
__global__ void build_kernel(const float* __restrict__ pos,
                             const int* __restrict__ src,
                             const int* __restrict__ dst,
                             float* __restrict__ dists,
                             int* __restrict__ cnt,
                             float4* __restrict__ edata,
                             int* __restrict__ eArr) {
    int e = blockIdx.x * TPB + threadIdx.x;
    if (e >= N_EDGES) return;
    int s = src[e];
    int d = dst[e];
    float rx = pos[3 * s + 0] - pos[3 * d + 0];
    float ry = pos[3 * s + 1] - pos[3 * d + 1];
    float rz = pos[3 * s + 2] - pos[3 * d + 2];
    float dist = sqrtf(rx * rx + ry * ry + rz * rz);
    dists[e] = dist;
    float inv = 1.0f / dist;
    int slot = atomicAdd(&cnt[s], 1);
    if (slot < CAP) {
        int idx = s * CAP + slot;
        float4 ed;
        ed.x = rx * inv;
        ed.y = ry * inv;
        ed.z = rz * inv;
        ed.w = __int_as_float(d);
        edata[idx] = ed;
        eArr[idx] = e;
    }
}

// ---- shared per-edge math (verified against reference) ----
__device__ __forceinline__ void edge_math(
    float ux, float uy, float uz, float R,
    float A0, const float A1[3], const float A2[9],
    float& acc0, float acc1[3], float acc2[9])
{
    float u[3] = {ux, uy, uz};
    float d1 = A1[0] * ux + A1[1] * uy + A1[2] * uz;   // A1.u
    float tA = A2[0] + A2[4] + A2[8];                   // tr(A2)
    float v0 = A2[0] * ux + A2[1] * uy + A2[2] * uz;    // A2 u
    float v1 = A2[3] * ux + A2[4] * uy + A2[5] * uz;
    float v2 = A2[6] * ux + A2[7] * uy + A2[8] * uz;
    float w0 = A2[0] * ux + A2[3] * uy + A2[6] * uz;    // A2^T u
    float w1 = A2[1] * ux + A2[4] * uy + A2[7] * uz;
    float w2 = A2[2] * ux + A2[5] * uy + A2[8] * uz;
    float q = ux * v0 + uy * v1 + uz * v2;              // u^T A2 u

    acc0 += R * (2.0f * A0 + d1 + 2.0f * tA + 2.0f * q);

    float svw[3] = {v0 + w0, v1 + w1, v2 + w2};
    float a0t = A0 + tA;
#pragma unroll
    for (int mm = 0; mm < 3; ++mm) {
        acc1[mm] += R * (A0 * u[mm] + 2.0f * A1[mm] + 2.0f * d1 * u[mm]
                         + svw[mm] + tA * u[mm]);
#pragma unroll
        for (int nn = 0; nn < 3; ++nn) {
            acc2[3 * mm + nn] += R * (a0t * u[mm] * u[nn] + A1[mm] * u[nn]
                                      + 2.0f * A2[3 * mm + nn]
                                      + 2.0f * svw[mm] * u[nn]);
        }
    }
}

// ---- issue all loads for one edge's h-set (+ radial inputs); no math on results ----
__device__ __forceinline__ void load_hset(
    const float* __restrict__ h0, const float* __restrict__ h1,
    const float* __restrict__ h2, const float* __restrict__ dists,
    int d, int e, int k,
    float& A0, float A1[3], float A2[9], float& r, float& nf)
{
    A0 = h0[d * NCH + k];
    const float* p1 = h1 + ((size_t)d * NCH + k) * 3;
    A1[0] = p1[0]; A1[1] = p1[1]; A1[2] = p1[2];
    const float* p2 = h2 + ((size_t)d * NCH + k) * 9;
#pragma unroll
    for (int q2 = 0; q2 < 9; ++q2) A2[q2] = p2[q2];
    // radial with the reference's faithful [K,E]->[E,K] reshape
    unsigned f = (unsigned)e * NCH + (unsigned)k;
    unsigned n_idx = f / (unsigned)N_EDGES;
    unsigned e_idx = f - n_idx * (unsigned)N_EDGES;
    r = dists[e_idx];
    nf = (float)(n_idx + 1);
}

__device__ __forceinline__ float radial_R(float nf, float r) {
    return 0.44721359549995794f * __sinf(nf * 0.3141592653589793f * r) / r;
}

// K2: main — persistent waves, one node at a time, pair-batched load->compute
__global__ __launch_bounds__(TPB, 6)
void node_wave_fast(const float* __restrict__ h0,
                    const float* __restrict__ h1,
                    const float* __restrict__ h2,
                    const int* __restrict__ cnt,
                    const float4* __restrict__ edata,
                    const int* __restrict__ eArr,
                    const float* __restrict__ dists,
                    float* __restrict__ out0,
                    float* __restrict__ out1,
                    float* __restrict__ out2) {
    int lane = threadIdx.x & 63;
    int k = lane & 15;
    int j = lane >> 4;
    int wid = blockIdx.x * (TPB >> 6) + (threadIdx.x >> 6);
    const int nw = NBLK_MAIN * (TPB >> 6);

    for (int node = wid; node < N_NODES; node += nw) {
        int base = node * CAP;
        // cnt + first two edata/eArr slots are independent: issue all in parallel.
        // Slots j and j+4 are always in-bounds of the row (j+4 <= 7 < CAP);
        // contents may be garbage when slot >= m -- gated by hasA/hasB below.
        int m = cnt[node];
        float4 edA = edata[base + j];
        float4 edB = edata[base + j + 4];
        int eA = eArr[base + j];
        int eB = eArr[base + j + 4];
        if (m > CAP) m = CAP;

        float acc0 = 0.0f;
        float acc1[3] = {0.0f, 0.0f, 0.0f};
        float acc2[9] = {0.0f, 0.0f, 0.0f, 0.0f, 0.0f, 0.0f, 0.0f, 0.0f, 0.0f};

        bool hasA = (j < m);
        bool hasB = (j + 4 < m);

        float A0A, A1A[3], A2A[9], rA, nfA;
        float A0B, A1B[3], A2B[9], rB, nfB;
        if (hasA) load_hset(h0, h1, h2, dists, __float_as_int(edA.w), eA, k,
                            A0A, A1A, A2A, rA, nfA);
        if (hasB) load_hset(h0, h1, h2, dists, __float_as_int(edB.w), eB, k,
                            A0B, A1B, A2B, rB, nfB);
        if (hasA) {
            float R = radial_R(nfA, rA);
            edge_math(edA.x, edA.y, edA.z, R, A0A, A1A, A2A, acc0, acc1, acc2);
        }
        if (hasB) {
            float R = radial_R(nfB, rB);
            edge_math(edB.x, edB.y, edB.z, R, A0B, A1B, A2B, acc0, acc1, acc2);
        }

        // tail: slots >= 8 (~14% of edges), same pair-batched pattern
        for (int c = j + 8; c < m; c += 8) {
            float4 eda = edata[base + c];
            int ea = eArr[base + c];
            bool hb = (c + 4) < m;
            float4 edb;
            int eb = 0;
            if (hb) { edb = edata[base + c + 4]; eb = eArr[base + c + 4]; }

            float a0a, a1a[3], a2a[9], ra, nfa;
            load_hset(h0, h1, h2, dists, __float_as_int(eda.w), ea, k,
                      a0a, a1a, a2a, ra, nfa);
            float a0b, a1b[3], a2b[9], rb, nfb;
            if (hb) load_hset(h0, h1, h2, dists, __float_as_int(edb.w), eb, k,
                              a0b, a1b, a2b, rb, nfb);

            {
                float R = radial_R(nfa, ra);
                edge_math(eda.x, eda.y, eda.z, R, a0a, a1a, a2a, acc0, acc1, acc2);
            }
            if (hb) {
                float R = radial_R(nfb, rb);
                edge_math(edb.x, edb.y, edb.z, R, a0b, a1b, a2b, acc0, acc1, acc2);
            }
        }

        // reduce across j (lanes xor 16, xor 32)
        acc0 += __shfl_xor(acc0, 16, 64);
        acc0 += __shfl_xor(acc0, 32, 64);
#pragma unroll
        for (int mm = 0; mm < 3; ++mm) {
            acc1[mm] += __shfl_xor(acc1[mm], 16, 64);
            acc1[mm] += __shfl_xor(acc1[mm], 32, 64);
        }
#pragma unroll
        for (int mm = 0; mm < 9; ++mm) {
            acc2[mm] += __shfl_xor(acc2[mm], 16, 64);
            acc2[mm] += __shfl_xor(acc2[mm], 32, 64);
        }

        if (j == 0) {
            int t = node * NCH + k;
            __builtin_nontemporal_store(acc0, &out0[t]);
            float* o1p = out1 + (size_t)t * 3;
#pragma unroll
            for (int mm = 0; mm < 3; ++mm)
                __builtin_nontemporal_store(acc1[mm], o1p + mm);
            float* o2p = out2 + (size_t)t * 9;
#pragma unroll
            for (int mm = 0; mm < 9; ++mm)
                __builtin_nontemporal_store(acc2[mm], o2p + mm);
        }
    }
}

// ======================= FALLBACK (R8 pipeline, small ws) =======================

__global__ void fb_geom_hist(const float* __restrict__ pos,
                             const int* __restrict__ src,
                             const int* __restrict__ dst,
                             float* __restrict__ dists,
                             int* __restrict__ cnt8,
                             int* __restrict__ rankArr) {
    int e = blockIdx.x * TPB + threadIdx.x;
    if (e >= N_EDGES) return;
    int stripe = blockIdx.x & (NSTRIPE - 1);
    int s = src[e];
    int d = dst[e];
    float rx = pos[3 * s + 0] - pos[3 * d + 0];
    float ry = pos[3 * s + 1] - pos[3 * d + 1];
    float rz = pos[3 * s + 2] - pos[3 * d + 2];
    dists[e] = sqrtf(rx * rx + ry * ry + rz * rz);
    rankArr[e] = atomicAdd(&cnt8[stripe * N_NODES + s], 1);
}

__global__ void fb_scan(const int* __restrict__ cnt8,
                        int* __restrict__ incl,
                        int* __restrict__ bsum) {
    __shared__ int sh[TPB];
    int tid = threadIdx.x;
    int i = blockIdx.x * TPB + tid;
    int tot = 0;
    if (i < N_NODES) {
#pragma unroll
        for (int c = 0; c < NSTRIPE; ++c) tot += cnt8[c * N_NODES + i];
    }
    sh[tid] = tot;
    __syncthreads();
    for (int s = 1; s < TPB; s <<= 1) {
        int x = 0;
        if (tid >= s) x = sh[tid - s];
        __syncthreads();
        if (tid >= s) sh[tid] += x;
        __syncthreads();
    }
    if (i < N_NODES) incl[i] = sh[tid];
    if (tid == TPB - 1) bsum[blockIdx.x] = sh[TPB - 1];
}

__global__ void fb_final(const int* __restrict__ cnt8,
                         const int* __restrict__ incl,
                         const int* __restrict__ bsum,
                         int* __restrict__ offsets,
                         int* __restrict__ copyBase) {
    __shared__ int sh[TPB];
    int tid = threadIdx.x;
    int b = blockIdx.x;
    sh[tid] = (tid < b) ? bsum[tid] : 0;
    __syncthreads();
    for (int s = 128; s > 0; s >>= 1) {
        if (tid < s) sh[tid] += sh[tid + s];
        __syncthreads();
    }
    int base = sh[0];
    int i = b * TPB + tid;
    if (i < N_NODES) {
        int cv[NSTRIPE];
        int tot = 0;
#pragma unroll
        for (int c = 0; c < NSTRIPE; ++c) { cv[c] = cnt8[c * N_NODES + i]; tot += cv[c]; }
        int off = base + incl[i] - tot;
        offsets[i] = off;
        int run = off;
#pragma unroll
        for (int c = 0; c < NSTRIPE; ++c) { copyBase[c * N_NODES + i] = run; run += cv[c]; }
    }
    if (b == 0 && tid == 0) offsets[N_NODES] = N_EDGES;
}

__global__ void fb_fill(const int* __restrict__ src,
                        const int* __restrict__ dst,
                        const float* __restrict__ pos,
                        const float* __restrict__ dists,
                        const int* __restrict__ copyBase,
                        const int* __restrict__ rankArr,
                        float4* __restrict__ edata,
                        int* __restrict__ csr) {
    int e = blockIdx.x * TPB + threadIdx.x;
    if (e >= N_EDGES) return;
    int stripe = blockIdx.x & (NSTRIPE - 1);
    int s = src[e];
    int d = dst[e];
    float rx = pos[3 * s + 0] - pos[3 * d + 0];
    float ry = pos[3 * s + 1] - pos[3 * d + 1];
    float rz = pos[3 * s + 2] - pos[3 * d + 2];
    float inv = 1.0f / dists[e];
    int slot = copyBase[stripe * N_NODES + s] + rankArr[e];
    float4 ed;
    ed.x = rx * inv;
    ed.y = ry * inv;
    ed.z = rz * inv;
    ed.w = __int_as_float(d);
    edata[slot] = ed;
    csr[slot] = e;
}

__global__ void fb_main(const float* __restrict__ h0,
                        const float* __restrict__ h1,
                        const float* __restrict__ h2,
                        const int* __restrict__ offsets,
                        const float4* __restrict__ edata,
                        const int* __restrict__ csr,
                        const float* __restrict__ dists,
                        float* __restrict__ out0,
                        float* __restrict__ out1,
                        float* __restrict__ out2) {
    int gid = blockIdx.x * TPB + threadIdx.x;
    int node = gid >> 6;
    if (node >= N_NODES) return;
    int lane = threadIdx.x & 63;
    int k = lane & 15;
    int j = lane >> 4;
    int beg = offsets[node];
    int end = offsets[node + 1];

    float acc0 = 0.0f;
    float acc1[3] = {0.0f, 0.0f, 0.0f};
    float acc2[9] = {0.0f, 0.0f, 0.0f, 0.0f, 0.0f, 0.0f, 0.0f, 0.0f, 0.0f};

    int i = beg + j;
    float4 ed;
    int e = 0;
    if (i < end) { ed = edata[i]; e = csr[i]; }
    while (i < end) {
        int inext = i + 4;
        float4 edn = ed;
        int en = e;
        if (inext < end) { edn = edata[inext]; en = csr[inext]; }

        int d = __float_as_int(ed.w);
        float a0, a1[3], a2[9], r, nf;
        load_hset(h0, h1, h2, dists, d, e, k, a0, a1, a2, r, nf);
        float R = radial_R(nf, r);
        edge_math(ed.x, ed.y, ed.z, R, a0, a1, a2, acc0, acc1, acc2);

        ed = edn;
        e = en;
        i = inext;
    }

    acc0 += __shfl_xor(acc0, 16, 64);
    acc0 += __shfl_xor(acc0, 32, 64);
#pragma unroll
    for (int mm = 0; mm < 3; ++mm) {
        acc1[mm] += __shfl_xor(acc1[mm], 16, 64);
        acc1[mm] += __shfl_xor(acc1[mm], 32, 64);
    }
#pragma unroll
    for (int mm = 0; mm < 9; ++mm) {
        acc2[mm] += __shfl_xor(acc2[mm], 16, 64);
        acc2[mm] += __shfl_xor(acc2[mm], 32, 64);
    }

    if (j == 0) {
        int t = node * NCH + k;
        out0[t] = acc0;
        float* o1p = out1 + (size_t)t * 3;
#pragma unroll
        for (int mm = 0; mm < 3; ++mm) o1p[mm] = acc1[mm];
        float* o2p = out2 + (size_t)t * 9;
#pragma unroll
        for (int mm = 0; mm < 9; ++mm) o2p[mm] = acc2[mm];
    }
}

// ======================= host =======================

extern "C" void kernel_launch(void* const* d_in, const int* in_sizes, int n_in,
                              void* d_out, int out_size, void* d_ws, size_t ws_size,
                              hipStream_t stream) {
    const float* h0  = (const float*)d_in[0];
    const float* h1  = (const float*)d_in[1];
    const float* h2  = (const float*)d_in[2];
    const float* pos = (const float*)d_in[3];
    // d_in[4] = channel_weights: dead in the reference dataflow
    const int* edge_index = (const int*)d_in[5];
    const int* src = edge_index;
    const int* dst = edge_index + N_EDGES;

    float* out = (float*)d_out;
    float* out0 = out;                                  // [N,16]
    float* out1 = out + (size_t)N_NODES * NCH;          // [N,16,3]
    float* out2 = out + (size_t)N_NODES * NCH * 4;      // [N,16,9]

    // fast-path workspace need: edata[N*CAP] f4 + eArr[N*CAP] int + dists[E] + cnt[N]
    size_t need = (size_t)N_NODES * CAP * 16 + (size_t)N_NODES * CAP * 4
                + (size_t)N_EDGES * 4 + (size_t)N_NODES * 4;

    if (ws_size >= need) {
        float4* edata = (float4*)d_ws;                           // [N*CAP] 38.4 MB
        int* eArr     = (int*)(edata + (size_t)N_NODES * CAP);   // [N*CAP]  9.6 MB
        float* dists  = (float*)(eArr + (size_t)N_NODES * CAP);  // [E]      1.6 MB
        int* cnt      = (int*)(dists + N_EDGES);                 // [N]      0.2 MB

        hipMemsetAsync(cnt, 0, N_NODES * sizeof(int), stream);
        build_kernel<<<NB_EDGES, TPB, 0, stream>>>(pos, src, dst, dists, cnt, edata, eArr);
        node_wave_fast<<<NBLK_MAIN, TPB, 0, stream>>>(
            h0, h1, h2, cnt, edata, eArr, dists, out0, out1, out2);
    } else {
        // R8 pipeline (~15 MB ws)
        float4* edata   = (float4*)d_ws;                            // [E]
        float*  dists   = (float*)(edata + N_EDGES);                // [E]
        int* cnt8       = (int*)(dists + N_EDGES);                  // [8][N]
        int* rankArr    = cnt8 + NSTRIPE * N_NODES;                 // [E]
        int* incl       = rankArr + N_EDGES;                        // [N]
        int* bsum       = incl + N_NODES;                           // [NBN]
        int* offsets    = bsum + 256;                               // [N+1]
        int* copyBase   = offsets + N_NODES + 1;                    // [8][N]
        int* csr        = copyBase + NSTRIPE * N_NODES;             // [E]

        hipMemsetAsync(cnt8, 0, NSTRIPE * N_NODES * sizeof(int), stream);
        fb_geom_hist<<<NB_EDGES, TPB, 0, stream>>>(pos, src, dst, dists, cnt8, rankArr);
        fb_scan<<<NBN, TPB, 0, stream>>>(cnt8, incl, bsum);
        fb_final<<<NBN, TPB, 0, stream>>>(cnt8, incl, bsum, offsets, copyBase);
        fb_fill<<<NB_EDGES, TPB, 0, stream>>>(src, dst, pos, dists, copyBase, rankArr, edata, csr);
        fb_main<<<(N_NODES * 64 + TPB - 1) / TPB, TPB, 0, stream>>>(
            h0, h1, h2, offsets, edata, csr, dists, out0, out1, out2);
    }
}

// Round 2
// 203.811 us; speedup vs baseline: 2.2229x; 2.2229x over previous
//
#include <hip/hip_runtime.h>
#include <math.h>

#define N_NODES   50000
#define N_EDGES   400000
#define NCH       16
#define CAP       48          // per-node edge capacity; P(deg>48 | lambda=8) ~ 1e-17
#define NSTRIPE   8
#define TPB       256
#define NBN       ((N_NODES + TPB - 1) / TPB)   // 196
#define NB_EDGES  ((N_EDGES + TPB - 1) / TPB)   // 1563
#define NBLK_MAIN 4096        // persistent grid for node_wave_fast (16384 waves)

// ======================= FAST PATH (bucketed, 3 dispatches) =======================

// K1: per-edge geometry + direct bucket write (no scan/fill phases)
__global__ void build_kernel(const float* __restrict__ pos,
                             const int* __restrict__ src,
                             const int* __restrict__ dst,
                             float* __restrict__ dists,
                             int* __restrict__ cnt,
                             float4* __restrict__ edata,
                             int* __restrict__ eArr) {
    int e = blockIdx.x * TPB + threadIdx.x;
    if (e >= N_EDGES) return;
    int s = src[e];
    int d = dst[e];
    float rx = pos[3 * s + 0] - pos[3 * d + 0];
    float ry = pos[3 * s + 1] - pos[3 * d + 1];
    float rz = pos[3 * s + 2] - pos[3 * d + 2];
    float dist = sqrtf(rx * rx + ry * ry + rz * rz);
    dists[e] = dist;
    float inv = 1.0f / dist;
    int slot = atomicAdd(&cnt[s], 1);
    if (slot < CAP) {
        int idx = s * CAP + slot;
        float4 ed;
        ed.x = rx * inv;
        ed.y = ry * inv;
        ed.z = rz * inv;
        ed.w = __int_as_float(d);
        edata[idx] = ed;
        eArr[idx] = e;
    }
}

// ---- shared per-edge math (verified against reference) ----
__device__ __forceinline__ void edge_math(
    float ux, float uy, float uz, float R,
    float A0, const float A1[3], const float A2[9],
    float& acc0, float acc1[3], float acc2[9])
{
    float u[3] = {ux, uy, uz};
    float d1 = A1[0] * ux + A1[1] * uy + A1[2] * uz;   // A1.u
    float tA = A2[0] + A2[4] + A2[8];                   // tr(A2)
    float v0 = A2[0] * ux + A2[1] * uy + A2[2] * uz;    // A2 u
    float v1 = A2[3] * ux + A2[4] * uy + A2[5] * uz;
    float v2 = A2[6] * ux + A2[7] * uy + A2[8] * uz;
    float w0 = A2[0] * ux + A2[3] * uy + A2[6] * uz;    // A2^T u
    float w1 = A2[1] * ux + A2[4] * uy + A2[7] * uz;
    float w2 = A2[2] * ux + A2[5] * uy + A2[8] * uz;
    float q = ux * v0 + uy * v1 + uz * v2;              // u^T A2 u

    acc0 += R * (2.0f * A0 + d1 + 2.0f * tA + 2.0f * q);

    float svw[3] = {v0 + w0, v1 + w1, v2 + w2};
    float a0t = A0 + tA;
#pragma unroll
    for (int mm = 0; mm < 3; ++mm) {
        acc1[mm] += R * (A0 * u[mm] + 2.0f * A1[mm] + 2.0f * d1 * u[mm]
                         + svw[mm] + tA * u[mm]);
#pragma unroll
        for (int nn = 0; nn < 3; ++nn) {
            acc2[3 * mm + nn] += R * (a0t * u[mm] * u[nn] + A1[mm] * u[nn]
                                      + 2.0f * A2[3 * mm + nn]
                                      + 2.0f * svw[mm] * u[nn]);
        }
    }
}

// ---- unconditional loads for one edge's h-set (+ radial inputs) ----
// d and e MUST already be clamped to valid ranges by the caller.
__device__ __forceinline__ void load_hset(
    const float* __restrict__ h0, const float* __restrict__ h1,
    const float* __restrict__ h2, const float* __restrict__ dists,
    int d, int e, int k,
    float& A0, float A1[3], float A2[9], float& r, float& nf)
{
    A0 = h0[d * NCH + k];
    const float* p1 = h1 + ((size_t)d * NCH + k) * 3;
    A1[0] = p1[0]; A1[1] = p1[1]; A1[2] = p1[2];
    const float* p2 = h2 + ((size_t)d * NCH + k) * 9;
#pragma unroll
    for (int q2 = 0; q2 < 9; ++q2) A2[q2] = p2[q2];
    // radial with the reference's faithful [K,E]->[E,K] reshape
    unsigned f = (unsigned)e * NCH + (unsigned)k;
    unsigned n_idx = f / (unsigned)N_EDGES;
    unsigned e_idx = f - n_idx * (unsigned)N_EDGES;
    r = dists[e_idx];
    nf = (float)(n_idx + 1);
}

__device__ __forceinline__ float radial_R(float nf, float r) {
    return 0.44721359549995794f * __sinf(nf * 0.3141592653589793f * r) / r;
}

// K2: main — persistent waves; branchless dual-edge batch + next-node meta prefetch.
// All loads unconditional (select-clamped indices); invalid-edge contributions are
// zero-gated through R (every accumulated term is linear in R, so this is exact).
__global__ void node_wave_fast(const float* __restrict__ h0,
                               const float* __restrict__ h1,
                               const float* __restrict__ h2,
                               const int* __restrict__ cnt,
                               const float4* __restrict__ edata,
                               const int* __restrict__ eArr,
                               const float* __restrict__ dists,
                               float* __restrict__ out0,
                               float* __restrict__ out1,
                               float* __restrict__ out2) {
    int lane = threadIdx.x & 63;
    int k = lane & 15;
    int j = lane >> 4;
    int wid = blockIdx.x * (TPB >> 6) + (threadIdx.x >> 6);
    const int nw = NBLK_MAIN * (TPB >> 6);
    if (wid >= N_NODES) return;

    int node = wid;
    int base = node * CAP;
    // node-entry meta: cnt + first two slots are independent addresses
    // (j and j+4 always within the CAP row); issued in parallel.
    int m = cnt[node];
    float4 edA = edata[base + j];
    float4 edB = edata[base + j + 4];
    int eA = eArr[base + j];
    int eB = eArr[base + j + 4];

    for (;;) {
        // ---- software-pipeline: issue next node's meta now, consume next iter ----
        int nnode = node + nw;
        bool hasNext = (nnode < N_NODES);
        int pnode = hasNext ? nnode : node;      // safe address when done
        int pbase = pnode * CAP;
        int m_n = cnt[pnode];
        float4 edA_n = edata[pbase + j];
        float4 edB_n = edata[pbase + j + 4];
        int eA_n = eArr[pbase + j];
        int eB_n = eArr[pbase + j + 4];

        int mc = m;
        if (mc > CAP) mc = CAP;
        bool vA = (j < mc);
        bool vB = (j + 4 < mc);
        // clamp indices for unconditional loads (garbage slots -> node 0 / edge 0)
        int dA = vA ? __float_as_int(edA.w) : 0;
        int dB = vB ? __float_as_int(edB.w) : 0;
        int eAs = vA ? eA : 0;
        int eBs = vB ? eB : 0;

        float A0A, A1A[3], A2A[9], rA, nfA;
        load_hset(h0, h1, h2, dists, dA, eAs, k, A0A, A1A, A2A, rA, nfA);
        float A0B, A1B[3], A2B[9], rB, nfB;
        load_hset(h0, h1, h2, dists, dB, eBs, k, A0B, A1B, A2B, rB, nfB);

        float acc0 = 0.0f;
        float acc1[3] = {0.0f, 0.0f, 0.0f};
        float acc2[9] = {0.0f, 0.0f, 0.0f, 0.0f, 0.0f, 0.0f, 0.0f, 0.0f, 0.0f};

        float RA = radial_R(nfA, rA);
        RA = vA ? RA : 0.0f;
        float RB = radial_R(nfB, rB);
        RB = vB ? RB : 0.0f;
        edge_math(edA.x, edA.y, edA.z, RA, A0A, A1A, A2A, acc0, acc1, acc2);
        edge_math(edB.x, edB.y, edB.z, RB, A0B, A1B, A2B, acc0, acc1, acc2);

        // tail: slots >= 8 (deg>8 nodes), same branchless dual pattern
        for (int c = j + 8; c < mc; c += 8) {
            bool vb = (c + 4) < mc;
            int ia = base + c;
            int ib = vb ? (base + c + 4) : ia;
            float4 eda = edata[ia];
            float4 edb = edata[ib];
            int ea = eArr[ia];
            int eb = vb ? eArr[ib] : 0;
            int da = __float_as_int(eda.w);
            int db = vb ? __float_as_int(edb.w) : 0;

            float a0a, a1a[3], a2a[9], ra, nfa;
            load_hset(h0, h1, h2, dists, da, ea, k, a0a, a1a, a2a, ra, nfa);
            float a0b, a1b[3], a2b[9], rb, nfb;
            load_hset(h0, h1, h2, dists, db, eb, k, a0b, a1b, a2b, rb, nfb);

            float Ra = radial_R(nfa, ra);
            float Rb = radial_R(nfb, rb);
            Rb = vb ? Rb : 0.0f;
            edge_math(eda.x, eda.y, eda.z, Ra, a0a, a1a, a2a, acc0, acc1, acc2);
            edge_math(edb.x, edb.y, edb.z, Rb, a0b, a1b, a2b, acc0, acc1, acc2);
        }

        // reduce across j (lanes xor 16, xor 32)
        acc0 += __shfl_xor(acc0, 16, 64);
        acc0 += __shfl_xor(acc0, 32, 64);
#pragma unroll
        for (int mm = 0; mm < 3; ++mm) {
            acc1[mm] += __shfl_xor(acc1[mm], 16, 64);
            acc1[mm] += __shfl_xor(acc1[mm], 32, 64);
        }
#pragma unroll
        for (int mm = 0; mm < 9; ++mm) {
            acc2[mm] += __shfl_xor(acc2[mm], 16, 64);
            acc2[mm] += __shfl_xor(acc2[mm], 32, 64);
        }

        if (j == 0) {
            int t = node * NCH + k;
            __builtin_nontemporal_store(acc0, &out0[t]);
            float* o1p = out1 + (size_t)t * 3;
#pragma unroll
            for (int mm = 0; mm < 3; ++mm)
                __builtin_nontemporal_store(acc1[mm], o1p + mm);
            float* o2p = out2 + (size_t)t * 9;
#pragma unroll
            for (int mm = 0; mm < 9; ++mm)
                __builtin_nontemporal_store(acc2[mm], o2p + mm);
        }

        if (!hasNext) break;
        node = nnode;
        base = pbase;
        m = m_n;
        edA = edA_n;
        edB = edB_n;
        eA = eA_n;
        eB = eB_n;
    }
}

// ======================= FALLBACK (R8 pipeline, small ws) =======================

__global__ void fb_geom_hist(const float* __restrict__ pos,
                             const int* __restrict__ src,
                             const int* __restrict__ dst,
                             float* __restrict__ dists,
                             int* __restrict__ cnt8,
                             int* __restrict__ rankArr) {
    int e = blockIdx.x * TPB + threadIdx.x;
    if (e >= N_EDGES) return;
    int stripe = blockIdx.x & (NSTRIPE - 1);
    int s = src[e];
    int d = dst[e];
    float rx = pos[3 * s + 0] - pos[3 * d + 0];
    float ry = pos[3 * s + 1] - pos[3 * d + 1];
    float rz = pos[3 * s + 2] - pos[3 * d + 2];
    dists[e] = sqrtf(rx * rx + ry * ry + rz * rz);
    rankArr[e] = atomicAdd(&cnt8[stripe * N_NODES + s], 1);
}

__global__ void fb_scan(const int* __restrict__ cnt8,
                        int* __restrict__ incl,
                        int* __restrict__ bsum) {
    __shared__ int sh[TPB];
    int tid = threadIdx.x;
    int i = blockIdx.x * TPB + tid;
    int tot = 0;
    if (i < N_NODES) {
#pragma unroll
        for (int c = 0; c < NSTRIPE; ++c) tot += cnt8[c * N_NODES + i];
    }
    sh[tid] = tot;
    __syncthreads();
    for (int s = 1; s < TPB; s <<= 1) {
        int x = 0;
        if (tid >= s) x = sh[tid - s];
        __syncthreads();
        if (tid >= s) sh[tid] += x;
        __syncthreads();
    }
    if (i < N_NODES) incl[i] = sh[tid];
    if (tid == TPB - 1) bsum[blockIdx.x] = sh[TPB - 1];
}

__global__ void fb_final(const int* __restrict__ cnt8,
                         const int* __restrict__ incl,
                         const int* __restrict__ bsum,
                         int* __restrict__ offsets,
                         int* __restrict__ copyBase) {
    __shared__ int sh[TPB];
    int tid = threadIdx.x;
    int b = blockIdx.x;
    sh[tid] = (tid < b) ? bsum[tid] : 0;
    __syncthreads();
    for (int s = 128; s > 0; s >>= 1) {
        if (tid < s) sh[tid] += sh[tid + s];
        __syncthreads();
    }
    int base = sh[0];
    int i = b * TPB + tid;
    if (i < N_NODES) {
        int cv[NSTRIPE];
        int tot = 0;
#pragma unroll
        for (int c = 0; c < NSTRIPE; ++c) { cv[c] = cnt8[c * N_NODES + i]; tot += cv[c]; }
        int off = base + incl[i] - tot;
        offsets[i] = off;
        int run = off;
#pragma unroll
        for (int c = 0; c < NSTRIPE; ++c) { copyBase[c * N_NODES + i] = run; run += cv[c]; }
    }
    if (b == 0 && tid == 0) offsets[N_NODES] = N_EDGES;
}

__global__ void fb_fill(const int* __restrict__ src,
                        const int* __restrict__ dst,
                        const float* __restrict__ pos,
                        const float* __restrict__ dists,
                        const int* __restrict__ copyBase,
                        const int* __restrict__ rankArr,
                        float4* __restrict__ edata,
                        int* __restrict__ csr) {
    int e = blockIdx.x * TPB + threadIdx.x;
    if (e >= N_EDGES) return;
    int stripe = blockIdx.x & (NSTRIPE - 1);
    int s = src[e];
    int d = dst[e];
    float rx = pos[3 * s + 0] - pos[3 * d + 0];
    float ry = pos[3 * s + 1] - pos[3 * d + 1];
    float rz = pos[3 * s + 2] - pos[3 * d + 2];
    float inv = 1.0f / dists[e];
    int slot = copyBase[stripe * N_NODES + s] + rankArr[e];
    float4 ed;
    ed.x = rx * inv;
    ed.y = ry * inv;
    ed.z = rz * inv;
    ed.w = __int_as_float(d);
    edata[slot] = ed;
    csr[slot] = e;
}

__global__ void fb_main(const float* __restrict__ h0,
                        const float* __restrict__ h1,
                        const float* __restrict__ h2,
                        const int* __restrict__ offsets,
                        const float4* __restrict__ edata,
                        const int* __restrict__ csr,
                        const float* __restrict__ dists,
                        float* __restrict__ out0,
                        float* __restrict__ out1,
                        float* __restrict__ out2) {
    int gid = blockIdx.x * TPB + threadIdx.x;
    int node = gid >> 6;
    if (node >= N_NODES) return;
    int lane = threadIdx.x & 63;
    int k = lane & 15;
    int j = lane >> 4;
    int beg = offsets[node];
    int end = offsets[node + 1];

    float acc0 = 0.0f;
    float acc1[3] = {0.0f, 0.0f, 0.0f};
    float acc2[9] = {0.0f, 0.0f, 0.0f, 0.0f, 0.0f, 0.0f, 0.0f, 0.0f, 0.0f};

    int i = beg + j;
    float4 ed;
    int e = 0;
    if (i < end) { ed = edata[i]; e = csr[i]; }
    while (i < end) {
        int inext = i + 4;
        float4 edn = ed;
        int en = e;
        if (inext < end) { edn = edata[inext]; en = csr[inext]; }

        int d = __float_as_int(ed.w);
        float a0, a1[3], a2[9], r, nf;
        load_hset(h0, h1, h2, dists, d, e, k, a0, a1, a2, r, nf);
        float R = radial_R(nf, r);
        edge_math(ed.x, ed.y, ed.z, R, a0, a1, a2, acc0, acc1, acc2);

        ed = edn;
        e = en;
        i = inext;
    }

    acc0 += __shfl_xor(acc0, 16, 64);
    acc0 += __shfl_xor(acc0, 32, 64);
#pragma unroll
    for (int mm = 0; mm < 3; ++mm) {
        acc1[mm] += __shfl_xor(acc1[mm], 16, 64);
        acc1[mm] += __shfl_xor(acc1[mm], 32, 64);
    }
#pragma unroll
    for (int mm = 0; mm < 9; ++mm) {
        acc2[mm] += __shfl_xor(acc2[mm], 16, 64);
        acc2[mm] += __shfl_xor(acc2[mm], 32, 64);
    }

    if (j == 0) {
        int t = node * NCH + k;
        out0[t] = acc0;
        float* o1p = out1 + (size_t)t * 3;
#pragma unroll
        for (int mm = 0; mm < 3; ++mm) o1p[mm] = acc1[mm];
        float* o2p = out2 + (size_t)t * 9;
#pragma unroll
        for (int mm = 0; mm < 9; ++mm) o2p[mm] = acc2[mm];
    }
}

// ======================= host =======================

extern "C" void kernel_launch(void* const* d_in, const int* in_sizes, int n_in,
                              void* d_out, int out_size, void* d_ws, size_t ws_size,
                              hipStream_t stream) {
    const float* h0  = (const float*)d_in[0];
    const float* h1  = (const float*)d_in[1];
    const float* h2  = (const float*)d_in[2];
    const float* pos = (const float*)d_in[3];
    // d_in[4] = channel_weights: dead in the reference dataflow
    const int* edge_index = (const int*)d_in[5];
    const int* src = edge_index;
    const int* dst = edge_index + N_EDGES;

    float* out = (float*)d_out;
    float* out0 = out;                                  // [N,16]
    float* out1 = out + (size_t)N_NODES * NCH;          // [N,16,3]
    float* out2 = out + (size_t)N_NODES * NCH * 4;      // [N,16,9]

    // fast-path workspace need: edata[N*CAP] f4 + eArr[N*CAP] int + dists[E] + cnt[N]
    size_t need = (size_t)N_NODES * CAP * 16 + (size_t)N_NODES * CAP * 4
                + (size_t)N_EDGES * 4 + (size_t)N_NODES * 4;

    if (ws_size >= need) {
        float4* edata = (float4*)d_ws;                           // [N*CAP] 38.4 MB
        int* eArr     = (int*)(edata + (size_t)N_NODES * CAP);   // [N*CAP]  9.6 MB
        float* dists  = (float*)(eArr + (size_t)N_NODES * CAP);  // [E]      1.6 MB
        int* cnt      = (int*)(dists + N_EDGES);                 // [N]      0.2 MB

        hipMemsetAsync(cnt, 0, N_NODES * sizeof(int), stream);
        build_kernel<<<NB_EDGES, TPB, 0, stream>>>(pos, src, dst, dists, cnt, edata, eArr);
        node_wave_fast<<<NBLK_MAIN, TPB, 0, stream>>>(
            h0, h1, h2, cnt, edata, eArr, dists, out0, out1, out2);
    } else {
        // R8 pipeline (~15 MB ws)
        float4* edata   = (float4*)d_ws;                            // [E]
        float*  dists   = (float*)(edata + N_EDGES);                // [E]
        int* cnt8       = (int*)(dists + N_EDGES);                  // [8][N]
        int* rankArr    = cnt8 + NSTRIPE * N_NODES;                 // [E]
        int* incl       = rankArr + N_EDGES;                        // [N]
        int* bsum       = incl + N_NODES;                           // [NBN]
        int* offsets    = bsum + 256;                               // [N+1]
        int* copyBase   = offsets + N_NODES + 1;                    // [8][N]
        int* csr        = copyBase + NSTRIPE * N_NODES;             // [E]

        hipMemsetAsync(cnt8, 0, NSTRIPE * N_NODES * sizeof(int), stream);
        fb_geom_hist<<<NB_EDGES, TPB, 0, stream>>>(pos, src, dst, dists, cnt8, rankArr);
        fb_scan<<<NBN, TPB, 0, stream>>>(cnt8, incl, bsum);
        fb_final<<<NBN, TPB, 0, stream>>>(cnt8, incl, bsum, offsets, copyBase);
        fb_fill<<<NB_EDGES, TPB, 0, stream>>>(src, dst, pos, dists, copyBase, rankArr, edata, csr);
        fb_main<<<(N_NODES * 64 + TPB - 1) / TPB, TPB, 0, stream>>>(
            h0, h1, h2, offsets, edata, csr, dists, out0, out1, out2);
    }
}

// Round 3
// 184.395 us; speedup vs baseline: 2.4569x; 1.1053x over previous
//
#include <hip/hip_runtime.h>
#include <math.h>

#define N_NODES   50000
#define N_EDGES   400000
#define NCH       16
#define CAP       48          // per-node edge capacity; P(deg>48 | lambda=8) ~ 1e-17
#define NSTRIPE   8
#define TPB       256
#define NBN       ((N_NODES + TPB - 1) / TPB)   // 196
#define NB_EDGES  ((N_EDGES + TPB - 1) / TPB)   // 1563

// ======================= FAST PATH (bucketed, 3 dispatches) =======================

// K1: per-edge geometry + direct bucket write of a SLIM 8B record {e, d}.
// (unit vector is recomputed in K2 from L2-resident pos; halves the scattered
//  RMW write traffic vs the old 16B+4B two-array record)
__global__ void build_kernel(const float* __restrict__ pos,
                             const int* __restrict__ src,
                             const int* __restrict__ dst,
                             float* __restrict__ dists,
                             int* __restrict__ cnt,
                             int2* __restrict__ ebuf) {
    int e = blockIdx.x * TPB + threadIdx.x;
    if (e >= N_EDGES) return;
    int s = src[e];
    int d = dst[e];
    float rx = pos[3 * s + 0] - pos[3 * d + 0];
    float ry = pos[3 * s + 1] - pos[3 * d + 1];
    float rz = pos[3 * s + 2] - pos[3 * d + 2];
    float dist = sqrtf(rx * rx + ry * ry + rz * rz);
    dists[e] = dist;
    int slot = atomicAdd(&cnt[s], 1);
    if (slot < CAP) {
        ebuf[s * CAP + slot] = make_int2(e, d);
    }
}

// ---- shared per-edge math (verified against reference) ----
__device__ __forceinline__ void edge_math(
    float ux, float uy, float uz, float R,
    float A0, const float A1[3], const float A2[9],
    float& acc0, float acc1[3], float acc2[9])
{
    float u[3] = {ux, uy, uz};
    float d1 = A1[0] * ux + A1[1] * uy + A1[2] * uz;   // A1.u
    float tA = A2[0] + A2[4] + A2[8];                   // tr(A2)
    float v0 = A2[0] * ux + A2[1] * uy + A2[2] * uz;    // A2 u
    float v1 = A2[3] * ux + A2[4] * uy + A2[5] * uz;
    float v2 = A2[6] * ux + A2[7] * uy + A2[8] * uz;
    float w0 = A2[0] * ux + A2[3] * uy + A2[6] * uz;    // A2^T u
    float w1 = A2[1] * ux + A2[4] * uy + A2[7] * uz;
    float w2 = A2[2] * ux + A2[5] * uy + A2[8] * uz;
    float q = ux * v0 + uy * v1 + uz * v2;              // u^T A2 u

    acc0 += R * (2.0f * A0 + d1 + 2.0f * tA + 2.0f * q);

    float svw[3] = {v0 + w0, v1 + w1, v2 + w2};
    float a0t = A0 + tA;
#pragma unroll
    for (int mm = 0; mm < 3; ++mm) {
        acc1[mm] += R * (A0 * u[mm] + 2.0f * A1[mm] + 2.0f * d1 * u[mm]
                         + svw[mm] + tA * u[mm]);
#pragma unroll
        for (int nn = 0; nn < 3; ++nn) {
            acc2[3 * mm + nn] += R * (a0t * u[mm] * u[nn] + A1[mm] * u[nn]
                                      + 2.0f * A2[3 * mm + nn]
                                      + 2.0f * svw[mm] * u[nn]);
        }
    }
}

// ---- loads for one edge's h-set (+ radial inputs) [fallback path format] ----
__device__ __forceinline__ void load_hset(
    const float* __restrict__ h0, const float* __restrict__ h1,
    const float* __restrict__ h2, const float* __restrict__ dists,
    int d, int e, int k,
    float& A0, float A1[3], float A2[9], float& r, float& nf)
{
    A0 = h0[d * NCH + k];
    const float* p1 = h1 + ((size_t)d * NCH + k) * 3;
    A1[0] = p1[0]; A1[1] = p1[1]; A1[2] = p1[2];
    const float* p2 = h2 + ((size_t)d * NCH + k) * 9;
#pragma unroll
    for (int q2 = 0; q2 < 9; ++q2) A2[q2] = p2[q2];
    // radial with the reference's faithful [K,E]->[E,K] reshape
    unsigned f = (unsigned)e * NCH + (unsigned)k;
    unsigned n_idx = f / (unsigned)N_EDGES;
    unsigned e_idx = f - n_idx * (unsigned)N_EDGES;
    r = dists[e_idx];
    nf = (float)(n_idx + 1);
}

__device__ __forceinline__ float radial_R(float nf, float r) {
    return 0.44721359549995794f * __sinf(nf * 0.3141592653589793f * r) / r;
}

// K2: main — one wave per node (lane = j*16+k), round-0 structure:
// slot prefetch (distance 4), plain stores, 36-48 VGPR target.
// The initial ebuf load is UNCONDITIONAL (address always in-bounds) so the
// cnt load and first record load issue in parallel.
__global__ void node_wave_fast(const float* __restrict__ h0,
                               const float* __restrict__ h1,
                               const float* __restrict__ h2,
                               const float* __restrict__ pos,
                               const int* __restrict__ cnt,
                               const int2* __restrict__ ebuf,
                               const float* __restrict__ dists,
                               float* __restrict__ out0,
                               float* __restrict__ out1,
                               float* __restrict__ out2) {
    int gid = blockIdx.x * TPB + threadIdx.x;
    int node = gid >> 6;
    if (node >= N_NODES) return;
    int lane = threadIdx.x & 63;
    int k = lane & 15;
    int j = lane >> 4;
    int base = node * CAP;

    // independent node-entry loads: cnt + first record + own position
    int m = cnt[node];
    int2 pk = ebuf[base + j];          // unconditional; consumed only if j < m
    float ps0 = pos[3 * node + 0];
    float ps1 = pos[3 * node + 1];
    float ps2 = pos[3 * node + 2];
    if (m > CAP) m = CAP;

    float acc0 = 0.0f;
    float acc1[3] = {0.0f, 0.0f, 0.0f};
    float acc2[9] = {0.0f, 0.0f, 0.0f, 0.0f, 0.0f, 0.0f, 0.0f, 0.0f, 0.0f};

    int c = j;
    while (c < m) {
        int cn = c + 4;
        int2 pkn = pk;
        if (cn < m) pkn = ebuf[base + cn];

        int e = pk.x;
        int d = pk.y;

        // independent loads: neighbor position, h-rows, radial dist
        float pd0 = pos[3 * d + 0];
        float pd1 = pos[3 * d + 1];
        float pd2 = pos[3 * d + 2];

        float A0 = h0[d * NCH + k];
        const float* a1p = h1 + ((size_t)d * NCH + k) * 3;
        float A1[3] = {a1p[0], a1p[1], a1p[2]};
        const float* a2p = h2 + ((size_t)d * NCH + k) * 9;
        float A2[9];
#pragma unroll
        for (int q2 = 0; q2 < 9; ++q2) A2[q2] = a2p[q2];

        // radial with the reference's faithful [K,E]->[E,K] reshape
        unsigned f = (unsigned)e * NCH + (unsigned)k;
        unsigned n_idx = f / (unsigned)N_EDGES;
        unsigned e_idx = f - n_idx * (unsigned)N_EDGES;
        float r = dists[e_idx];
        float R = 0.44721359549995794f *
                  __sinf((float)(n_idx + 1) * 0.3141592653589793f * r) / r;

        // unit vector recomputed exactly as build's expression (same numerics)
        float rx = ps0 - pd0;
        float ry = ps1 - pd1;
        float rz = ps2 - pd2;
        float dist = sqrtf(rx * rx + ry * ry + rz * rz);
        float inv = 1.0f / dist;
        float ux = rx * inv, uy = ry * inv, uz = rz * inv;

        edge_math(ux, uy, uz, R, A0, A1, A2, acc0, acc1, acc2);

        pk = pkn;
        c = cn;
    }

    // reduce across j (lanes xor 16, xor 32)
    acc0 += __shfl_xor(acc0, 16, 64);
    acc0 += __shfl_xor(acc0, 32, 64);
#pragma unroll
    for (int mm = 0; mm < 3; ++mm) {
        acc1[mm] += __shfl_xor(acc1[mm], 16, 64);
        acc1[mm] += __shfl_xor(acc1[mm], 32, 64);
    }
#pragma unroll
    for (int mm = 0; mm < 9; ++mm) {
        acc2[mm] += __shfl_xor(acc2[mm], 16, 64);
        acc2[mm] += __shfl_xor(acc2[mm], 32, 64);
    }

    if (j == 0) {
        int t = node * NCH + k;
        out0[t] = acc0;
        float* o1p = out1 + (size_t)t * 3;
#pragma unroll
        for (int mm = 0; mm < 3; ++mm) o1p[mm] = acc1[mm];
        float* o2p = out2 + (size_t)t * 9;
#pragma unroll
        for (int mm = 0; mm < 9; ++mm) o2p[mm] = acc2[mm];
    }
}

// ======================= FALLBACK (R8 pipeline, small ws) =======================

__global__ void fb_geom_hist(const float* __restrict__ pos,
                             const int* __restrict__ src,
                             const int* __restrict__ dst,
                             float* __restrict__ dists,
                             int* __restrict__ cnt8,
                             int* __restrict__ rankArr) {
    int e = blockIdx.x * TPB + threadIdx.x;
    if (e >= N_EDGES) return;
    int stripe = blockIdx.x & (NSTRIPE - 1);
    int s = src[e];
    int d = dst[e];
    float rx = pos[3 * s + 0] - pos[3 * d + 0];
    float ry = pos[3 * s + 1] - pos[3 * d + 1];
    float rz = pos[3 * s + 2] - pos[3 * d + 2];
    dists[e] = sqrtf(rx * rx + ry * ry + rz * rz);
    rankArr[e] = atomicAdd(&cnt8[stripe * N_NODES + s], 1);
}

__global__ void fb_scan(const int* __restrict__ cnt8,
                        int* __restrict__ incl,
                        int* __restrict__ bsum) {
    __shared__ int sh[TPB];
    int tid = threadIdx.x;
    int i = blockIdx.x * TPB + tid;
    int tot = 0;
    if (i < N_NODES) {
#pragma unroll
        for (int c = 0; c < NSTRIPE; ++c) tot += cnt8[c * N_NODES + i];
    }
    sh[tid] = tot;
    __syncthreads();
    for (int s = 1; s < TPB; s <<= 1) {
        int x = 0;
        if (tid >= s) x = sh[tid - s];
        __syncthreads();
        if (tid >= s) sh[tid] += x;
        __syncthreads();
    }
    if (i < N_NODES) incl[i] = sh[tid];
    if (tid == TPB - 1) bsum[blockIdx.x] = sh[TPB - 1];
}

__global__ void fb_final(const int* __restrict__ cnt8,
                         const int* __restrict__ incl,
                         const int* __restrict__ bsum,
                         int* __restrict__ offsets,
                         int* __restrict__ copyBase) {
    __shared__ int sh[TPB];
    int tid = threadIdx.x;
    int b = blockIdx.x;
    sh[tid] = (tid < b) ? bsum[tid] : 0;
    __syncthreads();
    for (int s = 128; s > 0; s >>= 1) {
        if (tid < s) sh[tid] += sh[tid + s];
        __syncthreads();
    }
    int base = sh[0];
    int i = b * TPB + tid;
    if (i < N_NODES) {
        int cv[NSTRIPE];
        int tot = 0;
#pragma unroll
        for (int c = 0; c < NSTRIPE; ++c) { cv[c] = cnt8[c * N_NODES + i]; tot += cv[c]; }
        int off = base + incl[i] - tot;
        offsets[i] = off;
        int run = off;
#pragma unroll
        for (int c = 0; c < NSTRIPE; ++c) { copyBase[c * N_NODES + i] = run; run += cv[c]; }
    }
    if (b == 0 && tid == 0) offsets[N_NODES] = N_EDGES;
}

__global__ void fb_fill(const int* __restrict__ src,
                        const int* __restrict__ dst,
                        const float* __restrict__ pos,
                        const float* __restrict__ dists,
                        const int* __restrict__ copyBase,
                        const int* __restrict__ rankArr,
                        float4* __restrict__ edata,
                        int* __restrict__ csr) {
    int e = blockIdx.x * TPB + threadIdx.x;
    if (e >= N_EDGES) return;
    int stripe = blockIdx.x & (NSTRIPE - 1);
    int s = src[e];
    int d = dst[e];
    float rx = pos[3 * s + 0] - pos[3 * d + 0];
    float ry = pos[3 * s + 1] - pos[3 * d + 1];
    float rz = pos[3 * s + 2] - pos[3 * d + 2];
    float inv = 1.0f / dists[e];
    int slot = copyBase[stripe * N_NODES + s] + rankArr[e];
    float4 ed;
    ed.x = rx * inv;
    ed.y = ry * inv;
    ed.z = rz * inv;
    ed.w = __int_as_float(d);
    edata[slot] = ed;
    csr[slot] = e;
}

__global__ void fb_main(const float* __restrict__ h0,
                        const float* __restrict__ h1,
                        const float* __restrict__ h2,
                        const int* __restrict__ offsets,
                        const float4* __restrict__ edata,
                        const int* __restrict__ csr,
                        const float* __restrict__ dists,
                        float* __restrict__ out0,
                        float* __restrict__ out1,
                        float* __restrict__ out2) {
    int gid = blockIdx.x * TPB + threadIdx.x;
    int node = gid >> 6;
    if (node >= N_NODES) return;
    int lane = threadIdx.x & 63;
    int k = lane & 15;
    int j = lane >> 4;
    int beg = offsets[node];
    int end = offsets[node + 1];

    float acc0 = 0.0f;
    float acc1[3] = {0.0f, 0.0f, 0.0f};
    float acc2[9] = {0.0f, 0.0f, 0.0f, 0.0f, 0.0f, 0.0f, 0.0f, 0.0f, 0.0f};

    int i = beg + j;
    float4 ed;
    int e = 0;
    if (i < end) { ed = edata[i]; e = csr[i]; }
    while (i < end) {
        int inext = i + 4;
        float4 edn = ed;
        int en = e;
        if (inext < end) { edn = edata[inext]; en = csr[inext]; }

        int d = __float_as_int(ed.w);
        float a0, a1[3], a2[9], r, nf;
        load_hset(h0, h1, h2, dists, d, e, k, a0, a1, a2, r, nf);
        float R = radial_R(nf, r);
        edge_math(ed.x, ed.y, ed.z, R, a0, a1, a2, acc0, acc1, acc2);

        ed = edn;
        e = en;
        i = inext;
    }

    acc0 += __shfl_xor(acc0, 16, 64);
    acc0 += __shfl_xor(acc0, 32, 64);
#pragma unroll
    for (int mm = 0; mm < 3; ++mm) {
        acc1[mm] += __shfl_xor(acc1[mm], 16, 64);
        acc1[mm] += __shfl_xor(acc1[mm], 32, 64);
    }
#pragma unroll
    for (int mm = 0; mm < 9; ++mm) {
        acc2[mm] += __shfl_xor(acc2[mm], 16, 64);
        acc2[mm] += __shfl_xor(acc2[mm], 32, 64);
    }

    if (j == 0) {
        int t = node * NCH + k;
        out0[t] = acc0;
        float* o1p = out1 + (size_t)t * 3;
#pragma unroll
        for (int mm = 0; mm < 3; ++mm) o1p[mm] = acc1[mm];
        float* o2p = out2 + (size_t)t * 9;
#pragma unroll
        for (int mm = 0; mm < 9; ++mm) o2p[mm] = acc2[mm];
    }
}

// ======================= host =======================

extern "C" void kernel_launch(void* const* d_in, const int* in_sizes, int n_in,
                              void* d_out, int out_size, void* d_ws, size_t ws_size,
                              hipStream_t stream) {
    const float* h0  = (const float*)d_in[0];
    const float* h1  = (const float*)d_in[1];
    const float* h2  = (const float*)d_in[2];
    const float* pos = (const float*)d_in[3];
    // d_in[4] = channel_weights: dead in the reference dataflow
    const int* edge_index = (const int*)d_in[5];
    const int* src = edge_index;
    const int* dst = edge_index + N_EDGES;

    float* out = (float*)d_out;
    float* out0 = out;                                  // [N,16]
    float* out1 = out + (size_t)N_NODES * NCH;          // [N,16,3]
    float* out2 = out + (size_t)N_NODES * NCH * 4;      // [N,16,9]

    // fast-path workspace: ebuf[N*CAP] int2 (19.2 MB) + dists[E] + cnt[N]
    size_t need = (size_t)N_NODES * CAP * 8 + (size_t)N_EDGES * 4 + (size_t)N_NODES * 4;

    if (ws_size >= need) {
        int2* ebuf   = (int2*)d_ws;                              // [N*CAP] 19.2 MB
        float* dists = (float*)(ebuf + (size_t)N_NODES * CAP);   // [E]      1.6 MB
        int* cnt     = (int*)(dists + N_EDGES);                  // [N]      0.2 MB

        hipMemsetAsync(cnt, 0, N_NODES * sizeof(int), stream);
        build_kernel<<<NB_EDGES, TPB, 0, stream>>>(pos, src, dst, dists, cnt, ebuf);
        node_wave_fast<<<(N_NODES * 64 + TPB - 1) / TPB, TPB, 0, stream>>>(
            h0, h1, h2, pos, cnt, ebuf, dists, out0, out1, out2);
    } else {
        // R8 pipeline (~15 MB ws)
        float4* edata   = (float4*)d_ws;                            // [E]
        float*  dists   = (float*)(edata + N_EDGES);                // [E]
        int* cnt8       = (int*)(dists + N_EDGES);                  // [8][N]
        int* rankArr    = cnt8 + NSTRIPE * N_NODES;                 // [E]
        int* incl       = rankArr + N_EDGES;                        // [N]
        int* bsum       = incl + N_NODES;                           // [NBN]
        int* offsets    = bsum + 256;                               // [N+1]
        int* copyBase   = offsets + N_NODES + 1;                    // [8][N]
        int* csr        = copyBase + NSTRIPE * N_NODES;             // [E]

        hipMemsetAsync(cnt8, 0, NSTRIPE * N_NODES * sizeof(int), stream);
        fb_geom_hist<<<NB_EDGES, TPB, 0, stream>>>(pos, src, dst, dists, cnt8, rankArr);
        fb_scan<<<NBN, TPB, 0, stream>>>(cnt8, incl, bsum);
        fb_final<<<NBN, TPB, 0, stream>>>(cnt8, incl, bsum, offsets, copyBase);
        fb_fill<<<NB_EDGES, TPB, 0, stream>>>(src, dst, pos, dists, copyBase, rankArr, edata, csr);
        fb_main<<<(N_NODES * 64 + TPB - 1) / TPB, TPB, 0, stream>>>(
            h0, h1, h2, offsets, edata, csr, dists, out0, out1, out2);
    }
}